// Round 1
// baseline (472.607 us; speedup 1.0000x reference)
//
#include <hip/hip_runtime.h>

// Problem constants (fixed by reference)
#define NN   20000
#define RR   11
#define BB   8
#define IND  300
#define OUTD 256
#define EE   640000
#define RN   (RR * NN)      // 220000 buckets, key = rel*N + src
#define KP2  320            // K padded to 10 * 32 for 16x16x32 MFMA
#define SBS  332            // LDS bf16 row stride (664B; 16 distinct banks over 16 rows)
#define NSCAN_BLOCKS 215    // ceil(220000 / 1024)
#define SME  256            // staged edges per (block=16 nodes, relation); mean ~46.5
#define FEATB 5860          // blocks converting features (5860*1024 >= 6,000,000)
#define WT2B  320           // blocks building wt: 256*320 / 256
#define HZB   860           // blocks zeroing hist: ceil(220000/256)
#define NODES_PER_BLK 16
#define MAIN_BLOCKS 1250    // 20000 / 16

typedef short bf16x8 __attribute__((ext_vector_type(8)));
typedef float f32x4  __attribute__((ext_vector_type(4)));

union U8 {
    bf16x8  v;
    ushort4 h[2];
    uint4   q;
};

__device__ inline unsigned short f2bf(float f) {
    union { float f; unsigned u; } x;
    x.f = f;
    unsigned u = x.u;
    u += 0x7fffu + ((u >> 16) & 1u);   // round-to-nearest-even
    return (unsigned short)(u >> 16);
}
__device__ inline float bflo(unsigned p) { return __uint_as_float(p << 16); }
__device__ inline float bfhi(unsigned p) { return __uint_as_float(p & 0xFFFF0000u); }
__device__ inline unsigned packbf(float x, float y) {
    return (unsigned)f2bf(x) | ((unsigned)f2bf(y) << 16);
}

// -------- fused prep: feat fp32->bf16, Wt[r][o][k] bf16 build, hist zeroing
// wt build: one thread per (o,k), loads 8 bases values ONCE, emits all 11 r.
__global__ __launch_bounds__(256) void k_prep(const float* __restrict__ feat,
                                              const float* __restrict__ comps,
                                              const float* __restrict__ bases,
                                              unsigned short* __restrict__ f2,
                                              unsigned short* __restrict__ wt,
                                              unsigned* __restrict__ hist,
                                              int feat_blocks) {
    const int b = blockIdx.x;
    if (b < feat_blocks) {
        const unsigned i = ((unsigned)b * 256u + threadIdx.x) * 4u;
        if (i < (unsigned)(NN * IND)) {
            const float4 v = *(const float4*)(feat + i);
            ushort4 o;
            o.x = f2bf(v.x); o.y = f2bf(v.y); o.z = f2bf(v.z); o.w = f2bf(v.w);
            *(ushort4*)(f2 + i) = o;
        }
        return;
    }
    const int b2 = b - feat_blocks;
    if (b2 < WT2B) {
        const unsigned idx = (unsigned)b2 * 256u + threadIdx.x;   // < 256*320
        const unsigned o   = idx / KP2;
        const unsigned k   = idx - o * KP2;
        float bk[BB];
#pragma unroll
        for (int bb = 0; bb < BB; ++bb)
            bk[bb] = (k < IND) ? bases[((unsigned)bb * IND + k) * OUTD + o] : 0.f;
#pragma unroll
        for (int r = 0; r < RR; ++r) {
            float acc = 0.f;
#pragma unroll
            for (int bb = 0; bb < BB; ++bb) acc += comps[r * BB + bb] * bk[bb];
            wt[((unsigned)r * OUTD + o) * KP2 + k] = f2bf(acc);
        }
        return;
    }
    const unsigned idx = (unsigned)(b2 - WT2B) * 256u + threadIdx.x;
    if (idx < RN) hist[idx] = 0u;
}

// ---------------------------------------------------------------- histogram
__global__ __launch_bounds__(256) void k_hist(const int* __restrict__ esrc,
                                              const int* __restrict__ erel,
                                              unsigned* __restrict__ hist) {
    const int e = blockIdx.x * 256 + threadIdx.x;           // exactly 640000
    const unsigned key = (unsigned)erel[e] * NN + (unsigned)esrc[e];
    atomicAdd(&hist[key], 1u);
}

// ------------------------------------------------- scan level 1 (1024/block)
__global__ __launch_bounds__(256) void k_scan1(const unsigned* __restrict__ hist,
                                               unsigned* __restrict__ off,
                                               unsigned* __restrict__ bsum) {
    __shared__ unsigned sc[256];
    const int tid = threadIdx.x;
    const unsigned base = blockIdx.x * 1024u + (unsigned)tid * 4u;
    unsigned v0 = (base + 0 < RN) ? hist[base + 0] : 0u;
    unsigned v1 = (base + 1 < RN) ? hist[base + 1] : 0u;
    unsigned v2 = (base + 2 < RN) ? hist[base + 2] : 0u;
    unsigned v3 = (base + 3 < RN) ? hist[base + 3] : 0u;
    const unsigned s = v0 + v1 + v2 + v3;
    sc[tid] = s;
    __syncthreads();
    for (int d = 1; d < 256; d <<= 1) {
        unsigned t = (tid >= d) ? sc[tid - d] : 0u;
        __syncthreads();
        sc[tid] += t;
        __syncthreads();
    }
    if (tid == 255) bsum[blockIdx.x] = sc[255];
    unsigned run = sc[tid] - s;                              // exclusive
    if (base + 0 < RN) off[base + 0] = run; run += v0;
    if (base + 1 < RN) off[base + 1] = run; run += v1;
    if (base + 2 < RN) off[base + 2] = run; run += v2;
    if (base + 3 < RN) off[base + 3] = run;
}

// ---------------------------- scan level 2: 64-lane shuffle scan
__global__ __launch_bounds__(64) void k_scan2(unsigned* __restrict__ bsum) {
    const int lane = threadIdx.x;
    unsigned v[4];
    unsigned tot = 0;
#pragma unroll
    for (int i = 0; i < 4; ++i) {
        const int idx = lane * 4 + i;
        v[i] = (idx < NSCAN_BLOCKS) ? bsum[idx] : 0u;
        tot += v[i];
    }
    unsigned sc = tot;
    for (int d = 1; d < 64; d <<= 1) {
        unsigned t = __shfl_up(sc, d, 64);
        if (lane >= d) sc += t;
    }
    unsigned run = sc - tot;                                 // exclusive over lanes
#pragma unroll
    for (int i = 0; i < 4; ++i) {
        const int idx = lane * 4 + i;
        if (idx < NSCAN_BLOCKS) bsum[idx] = run;
        run += v[i];
    }
}

// ------------------------------------------------ scan level 3 (+cursor copy)
__global__ __launch_bounds__(256) void k_scan3(unsigned* __restrict__ off,
                                               unsigned* __restrict__ off2,
                                               const unsigned* __restrict__ bsum) {
    const unsigned idx = blockIdx.x * 256u + threadIdx.x;
    if (idx < RN) {
        const unsigned v = off[idx] + bsum[idx >> 10];
        off[idx]  = v;
        off2[idx] = v;
    }
    if (idx == 0) off[RN] = EE;
}

// ------------------------------------------------------- counting-sort scatter
__global__ __launch_bounds__(256) void k_scatter(const int* __restrict__ esrc,
                                                 const int* __restrict__ erel,
                                                 const int* __restrict__ edst,
                                                 unsigned* __restrict__ off2,
                                                 unsigned* __restrict__ ssd) {
    const int e = blockIdx.x * 256 + threadIdx.x;           // exactly 640000
    const unsigned key = (unsigned)erel[e] * NN + (unsigned)esrc[e];
    const unsigned p = atomicAdd(&off2[key], 1u);
    ssd[p] = (unsigned)edst[e];                              // dst only; src = bucket
}

// ---------------------------------------------------------------- fused main
// 16 nodes/block, 512 threads (8 waves), ~12.6KB LDS -> 4 blocks/CU resident,
// grid 1250 (4.88 blocks/CU avg vs old 2.44: kill the occupancy starvation).
// Wave w gathers nodes 2w..2w+1 with a 2-deep edge prefetch pipeline (2 edges
// in flight), packs bf16 A rows, then 10 x v_mfma_f32_16x16x32_bf16 into two
// persistent 16x16 accs (o-stripe of 32 per wave). No output conflicts.
template<int USE_BF16>
__global__ __launch_bounds__(512, 8) void k_main(const float* __restrict__ feat,
                                                 const unsigned short* __restrict__ feat2,
                                                 const float* __restrict__ bias,
                                                 const unsigned* __restrict__ offs,
                                                 const unsigned* __restrict__ ssd,
                                                 const unsigned short* __restrict__ wt,
                                                 float* __restrict__ out) {
    __shared__ __align__(16) unsigned short sbf[NODES_PER_BLK * SBS];
    __shared__ unsigned sme[SME];
    __shared__ unsigned soffs[RR * 17];

    const int tid  = threadIdx.x;
    const int wave = tid >> 6;
    const int lane = tid & 63;
    const int hrow = lane & 15;      // MFMA 16x16: A row / B col / C col
    const int kgrp = lane >> 4;      // 0..3 k-group
    const int n0   = blockIdx.x * NODES_PER_BLK;
    const int o0   = wave * 32;      // each wave owns a 32-wide output stripe

    // stage per-(rel,node) edge offsets; zero the K-pad uints (150..165) once
    if (tid < RR * 17) {
        const int r = tid / 17, j = tid - r * 17;
        soffs[tid] = offs[r * NN + n0 + j];
    }
    if (tid < 256)
        ((unsigned*)sbf)[(tid >> 4) * (SBS / 2) + 150 + (tid & 15)] = 0u;

    f32x4 acc0, acc1;
#pragma unroll
    for (int i = 0; i < 4; ++i) { acc0[i] = 0.f; acc1[i] = 0.f; }

    __syncthreads();

    for (int r = 0; r < RR; ++r) {
        const unsigned* so  = soffs + r * 17;
        const unsigned e0v  = so[0];
        unsigned nE = so[16] - e0v;
        if (nE > SME) nE = SME;                              // impossible; safety
        for (unsigned j = (unsigned)tid; j < nE; j += 512u)
            sme[j] = ssd[e0v + j];
        __syncthreads();

#pragma unroll
        for (int g = 0; g < 2; ++g) {
            const int m = wave * 2 + g;
            const unsigned c0 = so[m], c1 = so[m + 1];
            if (USE_BF16) {
                float a0 = 0, a1 = 0, a2 = 0, a3 = 0, a4 = 0, a5 = 0;
                unsigned p0 = 0, p1 = 0, p2 = 0;
                if (c0 < c1) {                               // prime the pipeline
                    const unsigned d   = sme[c0 - e0v];
                    const unsigned* fp = (const unsigned*)feat2 + d * 150u;
                    p0 = fp[lane];
                    p1 = fp[lane + 64];
                    p2 = (lane < 22) ? fp[lane + 128] : 0u;
                }
                for (unsigned e = c0; e < c1; ++e) {
                    const unsigned q0 = p0, q1 = p1, q2 = p2;
                    if (e + 1 < c1) {                        // prefetch next edge
                        const unsigned d   = sme[e + 1 - e0v];
                        const unsigned* fp = (const unsigned*)feat2 + d * 150u;
                        p0 = fp[lane];
                        p1 = fp[lane + 64];
                        p2 = (lane < 22) ? fp[lane + 128] : 0u;
                    }
                    a0 += bflo(q0); a1 += bfhi(q0);
                    a2 += bflo(q1); a3 += bfhi(q1);
                    a4 += bflo(q2); a5 += bfhi(q2);
                }
                const float inv = (c1 > c0) ? 1.0f / (float)(c1 - c0) : 0.f;
                unsigned* sp = (unsigned*)sbf + m * (SBS / 2);
                sp[lane]      = packbf(a0 * inv, a1 * inv);
                sp[lane + 64] = packbf(a2 * inv, a3 * inv);
                if (lane < 22) sp[lane + 128] = packbf(a4 * inv, a5 * inv);
            } else {
                float a0 = 0, a1 = 0, a2 = 0, a3 = 0, a4 = 0;
                for (unsigned e = c0; e < c1; ++e) {
                    const unsigned d = sme[e - e0v];
                    const float* fp  = feat + (size_t)d * IND;
                    a0 += fp[lane];
                    a1 += fp[lane + 64];
                    a2 += fp[lane + 128];
                    a3 += fp[lane + 192];
                    if (lane < 44) a4 += fp[lane + 256];
                }
                const float inv = (c1 > c0) ? 1.0f / (float)(c1 - c0) : 0.f;
                unsigned short* sp = sbf + m * SBS;
                sp[lane]       = f2bf(a0 * inv);
                sp[lane + 64]  = f2bf(a1 * inv);
                sp[lane + 128] = f2bf(a2 * inv);
                sp[lane + 192] = f2bf(a3 * inv);
                if (lane < 44) sp[lane + 256] = f2bf(a4 * inv);
            }
        }
        __syncthreads();

        // --- MFMA: C[16 nodes x 32 outs] += A[16 x 320] * B[320 x 32]
        // frag layout (16x16x32): row/col = lane&15, k = ks*32 + 8*(lane>>4)+j
        const unsigned short* ab  = sbf + hrow * SBS + 8 * kgrp;
        const unsigned short* wb0 = wt + ((size_t)(r * OUTD + o0 + hrow) * KP2) + 8 * kgrp;
        const unsigned short* wb1 = wb0 + 16 * KP2;
#pragma unroll
        for (int ks = 0; ks < 10; ++ks) {
            const int kk = ks * 32;
            U8 a, b0, b1;
            a.h[0] = *(const ushort4*)(ab + kk);
            a.h[1] = *(const ushort4*)(ab + kk + 4);
            b0.q   = *(const uint4*)(wb0 + kk);
            b1.q   = *(const uint4*)(wb1 + kk);
            acc0 = __builtin_amdgcn_mfma_f32_16x16x32_bf16(a.v, b0.v, acc0, 0, 0, 0);
            acc1 = __builtin_amdgcn_mfma_f32_16x16x32_bf16(a.v, b1.v, acc1, 0, 0, 0);
        }
        // next sme/sbf writes are each behind >=1 barrier from these reads
    }

    // --- epilogue: C/D layout (16x16): col=lane&15, row=(lane>>4)*4+reg
    const int ob = o0 + hrow;
    const float bv0 = bias[ob];
    const float bv1 = bias[ob + 16];
#pragma unroll
    for (int reg = 0; reg < 4; ++reg) {
        const int node = 4 * kgrp + reg;
        out[(size_t)(n0 + node) * OUTD + ob]      = acc0[reg] + bv0;
        out[(size_t)(n0 + node) * OUTD + ob + 16] = acc1[reg] + bv1;
    }
}

extern "C" void kernel_launch(void* const* d_in, const int* in_sizes, int n_in,
                              void* d_out, int out_size, void* d_ws, size_t ws_size,
                              hipStream_t stream) {
    const float* feat  = (const float*)d_in[0];
    const float* comps = (const float*)d_in[1];
    const float* bases = (const float*)d_in[2];
    const float* bias  = (const float*)d_in[3];
    const int*   esrc  = (const int*)d_in[4];
    const int*   erel  = (const int*)d_in[5];
    const int*   edst  = (const int*)d_in[6];
    float* out = (float*)d_out;

    char* ws = (char*)d_ws;
    // ws layout (bytes), 64-aligned segments. ssd ALIASES hist: hist is dead
    // after k_scan1; ssd first written in k_scatter (stream-ordered, no race).
    unsigned short* wt    = (unsigned short*)(ws + 0);        // 1,802,240
    unsigned*       off   = (unsigned*)(ws + 1802240);        // 880,064 (incl pad)
    unsigned*       off2  = (unsigned*)(ws + 2682304);        // 880,000
    unsigned*       bsum  = (unsigned*)(ws + 3562304);        // 1,024
    unsigned*       hist  = (unsigned*)(ws + 3563328);        // 880,000 (dead after scan1)
    unsigned*       ssd   = (unsigned*)(ws + 3563328);        // 2,560,000 (alias hist)
    unsigned short* feat2 = (unsigned short*)(ws + 6123328);  // 12,000,000 -> 18,123,328

    // host-uniform (same every call): bf16 feature path only if scratch fits
    const bool use_bf16 = ws_size >= (size_t)18123328;
    const int  featb    = use_bf16 ? FEATB : 0;

    hipLaunchKernelGGL(k_prep,    dim3(featb + WT2B + HZB), dim3(256), 0, stream,
                       feat, comps, bases, feat2, wt, hist, featb);
    hipLaunchKernelGGL(k_hist,    dim3(2500), dim3(256), 0, stream, esrc, erel, hist);
    hipLaunchKernelGGL(k_scan1,   dim3(NSCAN_BLOCKS), dim3(256), 0, stream, hist, off, bsum);
    hipLaunchKernelGGL(k_scan2,   dim3(1),    dim3(64),  0, stream, bsum);
    hipLaunchKernelGGL(k_scan3,   dim3(860),  dim3(256), 0, stream, off, off2, bsum);
    hipLaunchKernelGGL(k_scatter, dim3(2500), dim3(256), 0, stream, esrc, erel, edst, off2, ssd);
    if (use_bf16)
        hipLaunchKernelGGL((k_main<1>), dim3(MAIN_BLOCKS), dim3(512), 0, stream,
                           feat, feat2, bias, off, ssd, wt, out);
    else
        hipLaunchKernelGGL((k_main<0>), dim3(MAIN_BLOCKS), dim3(512), 0, stream,
                           feat, feat2, bias, off, ssd, wt, out);

    (void)in_sizes; (void)n_in; (void)out_size; (void)ws_size;
}

// Round 2
// 358.854 us; speedup vs baseline: 1.3170x; 1.3170x over previous
//
#include <hip/hip_runtime.h>

// Problem constants (fixed by reference)
#define NN   20000
#define RR   11
#define BB   8
#define IND  300
#define OUTD 256
#define EE   640000
#define RN   (RR * NN)      // 220000 buckets, key = rel*N + src
#define KP   304            // K padded to 19 * 16 for 32x32x16 MFMA
#define SBS  308            // LDS bf16 row stride (616B; 2-way bank aliasing = free)
#define SBU  (SBS / 2)      // row stride in uints (154)
#define NSCAN_BLOCKS 215    // ceil(220000 / 1024)
#define FEATB 5860          // blocks converting features (5860*1024 >= 6,000,000)
#define WT2B  304           // blocks building wt: 256*304 == 256*KP
#define HZB   860           // blocks zeroing hist: ceil(220000/256)

typedef short bf16x8 __attribute__((ext_vector_type(8)));
typedef float f32x16 __attribute__((ext_vector_type(16)));

union U8 {
    bf16x8  v;
    ushort4 h[2];
    uint4   q;
};

__device__ inline unsigned short f2bf(float f) {
    union { float f; unsigned u; } x;
    x.f = f;
    unsigned u = x.u;
    u += 0x7fffu + ((u >> 16) & 1u);   // round-to-nearest-even
    return (unsigned short)(u >> 16);
}
__device__ inline float bflo(unsigned p) { return __uint_as_float(p << 16); }
__device__ inline float bfhi(unsigned p) { return __uint_as_float(p & 0xFFFF0000u); }
__device__ inline unsigned packbf(float x, float y) {
    return (unsigned)f2bf(x) | ((unsigned)f2bf(y) << 16);
}

// -------- fused prep: feat fp32->bf16, Wt[r][o][k] bf16 build, hist zeroing
// wt build: one thread per (o,k), loads 8 bases values ONCE, emits all 11 r.
__global__ __launch_bounds__(256) void k_prep(const float* __restrict__ feat,
                                              const float* __restrict__ comps,
                                              const float* __restrict__ bases,
                                              unsigned short* __restrict__ f2,
                                              unsigned short* __restrict__ wt,
                                              unsigned* __restrict__ hist,
                                              int feat_blocks) {
    const int b = blockIdx.x;
    if (b < feat_blocks) {
        const unsigned i = ((unsigned)b * 256u + threadIdx.x) * 4u;
        if (i < (unsigned)(NN * IND)) {
            const float4 v = *(const float4*)(feat + i);
            ushort4 o;
            o.x = f2bf(v.x); o.y = f2bf(v.y); o.z = f2bf(v.z); o.w = f2bf(v.w);
            *(ushort4*)(f2 + i) = o;
        }
        return;
    }
    const int b2 = b - feat_blocks;
    if (b2 < WT2B) {
        const unsigned idx = (unsigned)b2 * 256u + threadIdx.x;   // < 256*KP
        const unsigned o   = idx / KP;
        const unsigned k   = idx - o * KP;
        float bk[BB];
#pragma unroll
        for (int bb = 0; bb < BB; ++bb)
            bk[bb] = (k < IND) ? bases[((unsigned)bb * IND + k) * OUTD + o] : 0.f;
#pragma unroll
        for (int r = 0; r < RR; ++r) {
            float acc = 0.f;
#pragma unroll
            for (int bb = 0; bb < BB; ++bb) acc += comps[r * BB + bb] * bk[bb];
            wt[((unsigned)r * OUTD + o) * KP + k] = f2bf(acc);
        }
        return;
    }
    const unsigned idx = (unsigned)(b2 - WT2B) * 256u + threadIdx.x;
    if (idx < RN) hist[idx] = 0u;
}

// ---------------------------------------------------------------- histogram
__global__ __launch_bounds__(256) void k_hist(const int* __restrict__ esrc,
                                              const int* __restrict__ erel,
                                              unsigned* __restrict__ hist) {
    const int e = blockIdx.x * 256 + threadIdx.x;           // exactly 640000
    const unsigned key = (unsigned)erel[e] * NN + (unsigned)esrc[e];
    atomicAdd(&hist[key], 1u);
}

// ------------------------------------------------- scan level 1 (1024/block)
__global__ __launch_bounds__(256) void k_scan1(const unsigned* __restrict__ hist,
                                               unsigned* __restrict__ off,
                                               unsigned* __restrict__ bsum) {
    __shared__ unsigned sc[256];
    const int tid = threadIdx.x;
    const unsigned base = blockIdx.x * 1024u + (unsigned)tid * 4u;
    unsigned v0 = (base + 0 < RN) ? hist[base + 0] : 0u;
    unsigned v1 = (base + 1 < RN) ? hist[base + 1] : 0u;
    unsigned v2 = (base + 2 < RN) ? hist[base + 2] : 0u;
    unsigned v3 = (base + 3 < RN) ? hist[base + 3] : 0u;
    const unsigned s = v0 + v1 + v2 + v3;
    sc[tid] = s;
    __syncthreads();
    for (int d = 1; d < 256; d <<= 1) {
        unsigned t = (tid >= d) ? sc[tid - d] : 0u;
        __syncthreads();
        sc[tid] += t;
        __syncthreads();
    }
    if (tid == 255) bsum[blockIdx.x] = sc[255];
    unsigned run = sc[tid] - s;                              // exclusive
    if (base + 0 < RN) off[base + 0] = run; run += v0;
    if (base + 1 < RN) off[base + 1] = run; run += v1;
    if (base + 2 < RN) off[base + 2] = run; run += v2;
    if (base + 3 < RN) off[base + 3] = run;
}

// ------------- scan level 2+3 fused: per-block redundant bsum prefix reduce
__global__ __launch_bounds__(256) void k_scan3(unsigned* __restrict__ off,
                                               unsigned* __restrict__ off2,
                                               const unsigned* __restrict__ bsum) {
    __shared__ unsigned sS;
    const unsigned K = blockIdx.x >> 2;       // # level-1 blocks strictly before
    if (threadIdx.x < 64) {
        unsigned s = 0;
        for (unsigned i = threadIdx.x; i < K; i += 64u) s += bsum[i];
#pragma unroll
        for (int d = 1; d < 64; d <<= 1) s += __shfl_xor(s, d, 64);
        if (threadIdx.x == 0) sS = s;
    }
    __syncthreads();
    const unsigned idx = blockIdx.x * 256u + threadIdx.x;
    if (idx < RN) {
        const unsigned v = off[idx] + sS;
        off[idx]  = v;
        off2[idx] = v;
    }
    if (idx == 0) off[RN] = EE;
}

// ------------------------------------------------------- counting-sort scatter
__global__ __launch_bounds__(256) void k_scatter(const int* __restrict__ esrc,
                                                 const int* __restrict__ erel,
                                                 const int* __restrict__ edst,
                                                 unsigned* __restrict__ off2,
                                                 unsigned* __restrict__ ssd) {
    const int e = blockIdx.x * 256 + threadIdx.x;           // exactly 640000
    const unsigned key = (unsigned)erel[e] * NN + (unsigned)esrc[e];
    const unsigned p = atomicAdd(&off2[key], 1u);
    ssd[p] = (unsigned)edst[e];                              // dst only; src = bucket
}

// ------------------------------------------------- per-relation gather pieces
struct PreS { unsigned bnd, w0, nW, dsts; };

// PRE: read wave's 5 bucket boundaries from LDS, issue ONE coalesced load of
// the wave's whole per-relation edge list (contiguous in ssd). Issued before
// the MFMA phase so the load lands under it.
__device__ __forceinline__ PreS g_pre(const unsigned* soffs_r,
                                      const unsigned* __restrict__ ssd,
                                      int wave, int lane) {
    PreS s;
    s.bnd = (lane < 5) ? soffs_r[wave * 4 + lane] : 0u;
    s.w0  = __shfl(s.bnd, 0);
    s.nW  = __shfl(s.bnd, 4) - s.w0;
    s.dsts = 0u;
    if (s.nW <= 64u && (unsigned)lane < s.nW) s.dsts = ssd[s.w0 + (unsigned)lane];
    return s;
}

// BODY: 4-deep software-pipelined gather over the wave's edges, crossing
// bucket boundaries; finalize (scale + bf16-pack + sbf write) at boundaries.
template<int USE_BF16>
__device__ __forceinline__ void g_body(const PreS s,
                                       const float* __restrict__ feat,
                                       const unsigned short* __restrict__ feat2,
                                       const unsigned* __restrict__ ssd,
                                       unsigned short* sb, int wave, int lane) {
    if (USE_BF16) {
        float a0 = 0, a1 = 0, a2 = 0, a3 = 0, a4 = 0, a5 = 0;
        int g = 0;
        unsigned cg0 = 0;
        unsigned cg1 = __shfl(s.bnd, 1) - s.w0;
        auto FIN = [&]() {
            const unsigned cnt = cg1 - cg0;
            const float inv = cnt ? 1.0f / (float)cnt : 0.f;
            unsigned* sp = (unsigned*)sb + (wave * 4 + g) * SBU;
            sp[lane]      = packbf(a0 * inv, a1 * inv);
            sp[lane + 64] = packbf(a2 * inv, a3 * inv);
            if (lane < 22) sp[lane + 128] = packbf(a4 * inv, a5 * inv);
            a0 = a1 = a2 = a3 = a4 = a5 = 0.f;
            ++g; cg0 = cg1;
            const unsigned nb = __shfl(s.bnd, g < 4 ? g + 1 : 4) - s.w0;
            cg1 = (g < 4) ? nb : 0xFFFFFFFFu;
        };
        while (g < 4 && cg1 == 0u) FIN();                    // leading empties
        if (s.nW <= 64u) {
            // ---- fast path: modulo-4 register pipeline (static indexing)
            unsigned pa[4], pb[4], pc[4];
#pragma unroll
            for (int u = 0; u < 4; ++u) {
                pa[u] = pb[u] = pc[u] = 0u;
                if ((unsigned)u < s.nW) {
                    const unsigned d   = __shfl(s.dsts, u);
                    const unsigned* fp = (const unsigned*)feat2 + d * 150u;
                    pa[u] = fp[lane];
                    pb[u] = fp[lane + 64];
                    pc[u] = (lane < 22) ? fp[lane + 128] : 0u;
                }
            }
            for (unsigned tb = 0; tb < s.nW; tb += 4u) {
#pragma unroll
                for (int u = 0; u < 4; ++u) {
                    const unsigned t = tb + (unsigned)u;
                    if (t < s.nW) {
                        const unsigned q0 = pa[u], q1 = pb[u], q2 = pc[u];
                        if (t + 4u < s.nW) {                 // refill slot u
                            const unsigned d   = __shfl(s.dsts, (int)(t + 4u));
                            const unsigned* fp = (const unsigned*)feat2 + d * 150u;
                            pa[u] = fp[lane];
                            pb[u] = fp[lane + 64];
                            pc[u] = (lane < 22) ? fp[lane + 128] : 0u;
                        }
                        a0 += bflo(q0); a1 += bfhi(q0);
                        a2 += bflo(q1); a3 += bfhi(q1);
                        a4 += bflo(q2); a5 += bfhi(q2);
                        while (g < 4 && cg1 == t + 1u) FIN();
                    }
                }
            }
        } else {
            // ---- slow path (statistically never: nW mean 11.6, >64 ~1e-30)
            while (g < 4) {
                for (unsigned e = cg0; e < cg1; ++e) {
                    const unsigned d   = ssd[s.w0 + e];
                    const unsigned* fp = (const unsigned*)feat2 + d * 150u;
                    const unsigned q0 = fp[lane];
                    const unsigned q1 = fp[lane + 64];
                    const unsigned q2 = (lane < 22) ? fp[lane + 128] : 0u;
                    a0 += bflo(q0); a1 += bfhi(q0);
                    a2 += bflo(q1); a3 += bfhi(q1);
                    a4 += bflo(q2); a5 += bfhi(q2);
                }
                FIN();
            }
        }
    } else {
        // fp32-feature fallback (ws too small for feat2): simple per-bucket
        for (int g = 0; g < 4; ++g) {
            const unsigned c0 = __shfl(s.bnd, g), c1 = __shfl(s.bnd, g + 1);
            float a0 = 0, a1 = 0, a2 = 0, a3 = 0, a4 = 0;
            for (unsigned e = c0; e < c1; ++e) {
                const unsigned d = ssd[e];
                const float* fp  = feat + (size_t)d * IND;
                a0 += fp[lane];
                a1 += fp[lane + 64];
                a2 += fp[lane + 128];
                a3 += fp[lane + 192];
                if (lane < 44) a4 += fp[lane + 256];
            }
            const float inv = (c1 > c0) ? 1.0f / (float)(c1 - c0) : 0.f;
            unsigned short* sp = sb + (wave * 4 + g) * SBS;
            sp[lane]       = f2bf(a0 * inv);
            sp[lane + 64]  = f2bf(a1 * inv);
            sp[lane + 128] = f2bf(a2 * inv);
            sp[lane + 192] = f2bf(a3 * inv);
            if (lane < 44) sp[lane + 256] = f2bf(a4 * inv);
        }
    }
}

// ---------------------------------------------------------------- fused main
// 32 nodes/block, 512 threads (8 waves), 625 blocks (all co-resident, 3/CU
// cap). Per relation: edge list in REGISTERS (1 coalesced ssd load + shfl
// broadcast -- no sme staging, no staging barrier), 4-deep gather pipeline
// crossing bucket boundaries, double-buffered sbf (1 barrier/relation) with
// the next relation's edge-list load issued before the MFMA phase.
template<int USE_BF16>
__global__ __launch_bounds__(512, 6) void k_main(const float* __restrict__ feat,
                                                 const unsigned short* __restrict__ feat2,
                                                 const float* __restrict__ bias,
                                                 const unsigned* __restrict__ offs,
                                                 const unsigned* __restrict__ ssd,
                                                 const unsigned short* __restrict__ wt,
                                                 float* __restrict__ out) {
    __shared__ __align__(16) unsigned short sbf[2][32 * SBS];
    __shared__ unsigned soffs[RR * 33];

    const int tid  = threadIdx.x;
    const int wave = tid >> 6;
    const int lane = tid & 63;
    const int row  = lane & 31;      // MFMA: A row / B col / C col
    const int q    = lane >> 5;
    const int n0   = blockIdx.x * 32;
    const int o0   = wave * 32;      // each wave owns a 32-wide output stripe

    if (tid < RR * 33) {
        const int r = tid / 33, j = tid - r * 33;
        soffs[tid] = offs[r * NN + n0 + j];
    }
    // zero K-pad uints (150..153) of every row in BOTH buffers, once
    if (tid < 256)
        ((unsigned*)sbf)[(tid >> 7) * (32 * SBU) + ((tid >> 2) & 31) * SBU
                         + 150 + (tid & 3)] = 0u;

    f32x16 acc;
#pragma unroll
    for (int i = 0; i < 16; ++i) acc[i] = 0.f;

    __syncthreads();

    // prologue: gather relation 0 into buffer 0
    {
        PreS s0 = g_pre(soffs, ssd, wave, lane);
        g_body<USE_BF16>(s0, feat, feat2, ssd, &sbf[0][0], wave, lane);
    }
    __syncthreads();

    for (int r = 0; r < RR; ++r) {
        PreS sn = {};
        if (r + 1 < RR) sn = g_pre(soffs + (r + 1) * 33, ssd, wave, lane);

        // --- MFMA: C[32 nodes x 32 outs] += A[32 x 304] * B[304 x 32]
        {
            const unsigned short* wb = wt + ((size_t)(r * OUTD + o0 + row)) * KP + 8 * q;
            const unsigned short* ab = &sbf[r & 1][0] + row * SBS + 8 * q;
#pragma unroll
            for (int ks = 0; ks < 19; ++ks) {
                const int kk = ks * 16;
                U8 a, b;
                a.h[0] = *(const ushort4*)(ab + kk);
                a.h[1] = *(const ushort4*)(ab + kk + 4);
                b.q    = *(const uint4*)(wb + kk);
                acc = __builtin_amdgcn_mfma_f32_32x32x16_bf16(a.v, b.v, acc, 0, 0, 0);
            }
        }

        if (r + 1 < RR) {
            g_body<USE_BF16>(sn, feat, feat2, ssd, &sbf[(r + 1) & 1][0], wave, lane);
            __syncthreads();
        }
    }

    // --- epilogue: C/D layout col=lane&31, row=(reg&3)+8*(reg>>2)+4*(lane>>5)
    const int o = o0 + row;
    const float bv = bias[o];
#pragma unroll
    for (int reg = 0; reg < 16; ++reg) {
        const int node = (reg & 3) + 8 * (reg >> 2) + 4 * q;
        out[(size_t)(n0 + node) * OUTD + o] = acc[reg] + bv;
    }
}

extern "C" void kernel_launch(void* const* d_in, const int* in_sizes, int n_in,
                              void* d_out, int out_size, void* d_ws, size_t ws_size,
                              hipStream_t stream) {
    const float* feat  = (const float*)d_in[0];
    const float* comps = (const float*)d_in[1];
    const float* bases = (const float*)d_in[2];
    const float* bias  = (const float*)d_in[3];
    const int*   esrc  = (const int*)d_in[4];
    const int*   erel  = (const int*)d_in[5];
    const int*   edst  = (const int*)d_in[6];
    float* out = (float*)d_out;

    char* ws = (char*)d_ws;
    // ws layout (bytes), 64-aligned segments. ssd ALIASES hist: hist is dead
    // after k_scan1; ssd first written in k_scatter (stream-ordered, no race).
    unsigned short* wt    = (unsigned short*)(ws + 0);        // 1,712,128
    unsigned*       off   = (unsigned*)(ws + 1712128);        // 880,064 (incl pad)
    unsigned*       off2  = (unsigned*)(ws + 2592192);        // 880,000
    unsigned*       bsum  = (unsigned*)(ws + 3472192);        // 1,024
    unsigned*       hist  = (unsigned*)(ws + 3473216);        // 880,000 (dead after scan1)
    unsigned*       ssd   = (unsigned*)(ws + 3473216);        // 2,560,000 (alias hist)
    unsigned short* feat2 = (unsigned short*)(ws + 6033216);  // 12,000,000 -> 18,033,216

    // host-uniform (same every call): bf16 feature path only if scratch fits
    const bool use_bf16 = ws_size >= (size_t)18033216;
    const int  featb    = use_bf16 ? FEATB : 0;

    hipLaunchKernelGGL(k_prep,    dim3(featb + WT2B + HZB), dim3(256), 0, stream,
                       feat, comps, bases, feat2, wt, hist, featb);
    hipLaunchKernelGGL(k_hist,    dim3(2500), dim3(256), 0, stream, esrc, erel, hist);
    hipLaunchKernelGGL(k_scan1,   dim3(NSCAN_BLOCKS), dim3(256), 0, stream, hist, off, bsum);
    hipLaunchKernelGGL(k_scan3,   dim3(860),  dim3(256), 0, stream, off, off2, bsum);
    hipLaunchKernelGGL(k_scatter, dim3(2500), dim3(256), 0, stream, esrc, erel, edst, off2, ssd);
    if (use_bf16)
        hipLaunchKernelGGL((k_main<1>), dim3(625), dim3(512), 0, stream,
                           feat, feat2, bias, off, ssd, wt, out);
    else
        hipLaunchKernelGGL((k_main<0>), dim3(625), dim3(512), 0, stream,
                           feat, feat2, bias, off, ssd, wt, out);

    (void)in_sizes; (void)n_in; (void)out_size; (void)ws_size;
}